// Round 2
// baseline (373.851 us; speedup 1.0000x reference)
//
#include <hip/hip_runtime.h>

// ---------------- problem constants ----------------
#define CC   5
#define MHW  512
#define NIM  2048
// model spectrum slab: rows [R_LO, R_LO+NRM), cols [0, NCM)
// sampled region is rows [510,1556), cols [0,537) -- slab padded to 64-multiples
#define R_LO 488
#define NRM  1088
#define NCM  576

#define PSM  41
#define NPM  192
#define PR_LO 40
#define PNR  112
#define PNC  56

#define PSO  61
#define NPO  256
#define NCO  129

#define TT   257
#define KXN  129
#define OBS  220

#define DPI 3.14159265358979323846264338327950288

static __device__ __forceinline__ float2 cmulf2(float2 a, float2 b) {
    return make_float2(a.x * b.x - a.y * b.y, a.x * b.y + a.y * b.x);
}

// ---------------- twiddle tables (global) ----------------
// W1[c*512+x] = exp(-2*pi*i*c*x/2048), c in [0,NCM)
__global__ void fill_w1(float2* __restrict__ W1) {
    int idx = blockIdx.x * 256 + threadIdx.x;
    if (idx >= NCM * MHW) return;
    int c = idx >> 9, x = idx & 511;
    int t = (c * x) & (NIM - 1);
    double a = -2.0 * DPI * (double)t / (double)NIM;
    W1[idx] = make_float2((float)cos(a), (float)sin(a));
}

// W2[m*512+y] = exp(-2*pi*i*ky*y/2048), ky = m + R_LO - 1024
__global__ void fill_w2(float2* __restrict__ W2) {
    int idx = blockIdx.x * 256 + threadIdx.x;
    if (idx >= NRM * MHW) return;
    int m = idx >> 9, y = idx & 511;
    int ky = m + (R_LO - 1024);
    int t = (ky * y) % NIM; if (t < 0) t += NIM;
    double a = -2.0 * DPI * (double)t / (double)NIM;
    W2[idx] = make_float2((float)cos(a), (float)sin(a));
}

// ---------------- stage 1: T1[m][c] = sum_x model[m][x] * W1[c][x] ----------------
// m = ch*512+y in [0,2560), c in [0,576), K=512.  real x complex.
__global__ __launch_bounds__(256) void gemm_m1(const float* __restrict__ A,
                                               const float2* __restrict__ W,
                                               float2* __restrict__ T1) {
    __shared__ float  As[16][64 + 1];
    __shared__ float2 Ws[16][64];
    int bm = blockIdx.x * 64, bn = blockIdx.y * 64;
    int tid = threadIdx.x;
    int tx = tid & 15, ty = tid >> 4;
    float2 acc[4][4];
    #pragma unroll
    for (int i = 0; i < 4; i++)
        #pragma unroll
        for (int j = 0; j < 4; j++) acc[i][j] = make_float2(0.f, 0.f);
    for (int k0 = 0; k0 < 512; k0 += 16) {
        #pragma unroll
        for (int l = 0; l < 4; l++) {
            int idx = tid + l * 256;
            int ml = idx >> 4, kl = idx & 15;
            As[kl][ml] = A[(bm + ml) * 512 + k0 + kl];
        }
        #pragma unroll
        for (int l = 0; l < 4; l++) {
            int idx = tid + l * 256;
            int nl = idx >> 4, kl = idx & 15;
            Ws[kl][nl] = W[(bn + nl) * 512 + k0 + kl];
        }
        __syncthreads();
        #pragma unroll
        for (int k = 0; k < 16; k++) {
            float a[4]; float2 w[4];
            #pragma unroll
            for (int i = 0; i < 4; i++) a[i] = As[k][ty + 16 * i];
            #pragma unroll
            for (int j = 0; j < 4; j++) w[j] = Ws[k][tx + 16 * j];
            #pragma unroll
            for (int i = 0; i < 4; i++)
                #pragma unroll
                for (int j = 0; j < 4; j++) {
                    acc[i][j].x = fmaf(a[i], w[j].x, acc[i][j].x);
                    acc[i][j].y = fmaf(a[i], w[j].y, acc[i][j].y);
                }
        }
        __syncthreads();
    }
    #pragma unroll
    for (int i = 0; i < 4; i++)
        #pragma unroll
        for (int j = 0; j < 4; j++) {
            int m = bm + ty + 16 * i, n = bn + tx + 16 * j;
            T1[m * NCM + n] = acc[i][j];
        }
}

// ---------------- stage 2: Fm[ch][m][n] = sum_k W2[m][k] * T1[ch][k][n] ----------------
// M=1088, N=576, K=512, complex x complex, batched over 5 channels.
__global__ __launch_bounds__(256) void gemm_m2(const float2* __restrict__ W2,
                                               const float2* __restrict__ T1,
                                               float2* __restrict__ Fm) {
    __shared__ float2 As[16][64 + 1];
    __shared__ float2 Bs[16][64];
    int bm = blockIdx.x * 64, bn = blockIdx.y * 64, ch = blockIdx.z;
    const float2* B = T1 + (size_t)ch * 512 * NCM;
    int tid = threadIdx.x;
    int tx = tid & 15, ty = tid >> 4;
    float2 acc[4][4];
    #pragma unroll
    for (int i = 0; i < 4; i++)
        #pragma unroll
        for (int j = 0; j < 4; j++) acc[i][j] = make_float2(0.f, 0.f);
    for (int k0 = 0; k0 < 512; k0 += 16) {
        #pragma unroll
        for (int l = 0; l < 4; l++) {
            int idx = tid + l * 256;
            int ml = idx >> 4, kl = idx & 15;
            As[kl][ml] = W2[(bm + ml) * 512 + k0 + kl];
        }
        #pragma unroll
        for (int l = 0; l < 4; l++) {
            int idx = tid + l * 256;
            int kl = idx >> 6, nl = idx & 63;
            Bs[kl][nl] = B[(k0 + kl) * NCM + bn + nl];
        }
        __syncthreads();
        #pragma unroll
        for (int k = 0; k < 16; k++) {
            float2 a[4], b[4];
            #pragma unroll
            for (int i = 0; i < 4; i++) a[i] = As[k][ty + 16 * i];
            #pragma unroll
            for (int j = 0; j < 4; j++) b[j] = Bs[k][tx + 16 * j];
            #pragma unroll
            for (int i = 0; i < 4; i++)
                #pragma unroll
                for (int j = 0; j < 4; j++) {
                    acc[i][j].x = fmaf(a[i].x, b[j].x, acc[i][j].x);
                    acc[i][j].x = fmaf(-a[i].y, b[j].y, acc[i][j].x);
                    acc[i][j].y = fmaf(a[i].x, b[j].y, acc[i][j].y);
                    acc[i][j].y = fmaf(a[i].y, b[j].x, acc[i][j].y);
                }
        }
        __syncthreads();
    }
    float2* Fo = Fm + (size_t)ch * NRM * NCM;
    #pragma unroll
    for (int i = 0; i < 4; i++)
        #pragma unroll
        for (int j = 0; j < 4; j++) {
            int m = bm + ty + 16 * i, n = bn + tx + 16 * j;
            Fo[m * NCM + n] = acc[i][j];
        }
}

// ---------------- psf_model partial DFT (tiny) ----------------
__global__ void psf_m1(const float* __restrict__ psf, float2* __restrict__ Tp) {
    __shared__ float2 tbl[NPM];
    int tid = threadIdx.x;
    for (int t = tid; t < NPM; t += 256) {
        double a = -2.0 * DPI * (double)t / (double)NPM;
        tbl[t] = make_float2((float)cos(a), (float)sin(a));
    }
    __syncthreads();
    int idx = blockIdx.x * 256 + tid;
    if (idx >= CC * PSM * PNC) return;
    int c = idx % PNC, y = (idx / PNC) % PSM, ch = idx / (PNC * PSM);
    const float* p = psf + (ch * PSM + y) * PSM;
    float2 acc = make_float2(0.f, 0.f);
    for (int x = 0; x < PSM; x++) {
        float2 w = tbl[(c * x) % NPM];
        float v = p[x];
        acc.x = fmaf(v, w.x, acc.x);
        acc.y = fmaf(v, w.y, acc.y);
    }
    Tp[idx] = acc;
}

__global__ void psf_m2(const float2* __restrict__ Tp, float2* __restrict__ Fp) {
    __shared__ float2 tbl[NPM];
    int tid = threadIdx.x;
    for (int t = tid; t < NPM; t += 256) {
        double a = -2.0 * DPI * (double)t / (double)NPM;
        tbl[t] = make_float2((float)cos(a), (float)sin(a));
    }
    __syncthreads();
    int idx = blockIdx.x * 256 + tid;
    if (idx >= CC * PNR * PNC) return;
    int c = idx % PNC, rr = (idx / PNC) % PNR, ch = idx / (PNC * PNR);
    int ky = rr + (PR_LO - 96);
    const float2* t = Tp + (ch * PSM) * PNC + c;
    float2 acc = make_float2(0.f, 0.f);
    for (int y = 0; y < PSM; y++) {
        int tt = (ky * y) % NPM; if (tt < 0) tt += NPM;
        float2 w = tbl[tt];
        float2 v = t[y * PNC];
        acc.x = fmaf(v.x, w.x, acc.x); acc.x = fmaf(-v.y, w.y, acc.x);
        acc.y = fmaf(v.x, w.y, acc.y); acc.y = fmaf(v.y, w.x, acc.y);
    }
    Fp[idx] = acc;
}

// ---------------- psf_obs partial DFT (tiny, full 256x129 grid) ----------------
__global__ void psf_o1(const float* __restrict__ psf, float2* __restrict__ To) {
    __shared__ float2 tbl[NPO];
    int tid = threadIdx.x;
    for (int t = tid; t < NPO; t += 256) {
        double a = -2.0 * DPI * (double)t / (double)NPO;
        tbl[t] = make_float2((float)cos(a), (float)sin(a));
    }
    __syncthreads();
    int idx = blockIdx.x * 256 + tid;
    if (idx >= CC * PSO * NCO) return;
    int c = idx % NCO, y = (idx / NCO) % PSO, ch = idx / (NCO * PSO);
    const float* p = psf + (ch * PSO + y) * PSO;
    float2 acc = make_float2(0.f, 0.f);
    for (int x = 0; x < PSO; x++) {
        float2 w = tbl[(c * x) & (NPO - 1)];
        float v = p[x];
        acc.x = fmaf(v, w.x, acc.x);
        acc.y = fmaf(v, w.y, acc.y);
    }
    To[idx] = acc;
}

__global__ void psf_o2(const float2* __restrict__ To, float2* __restrict__ Fo) {
    __shared__ float2 tbl[NPO];
    int tid = threadIdx.x;
    for (int t = tid; t < NPO; t += 256) {
        double a = -2.0 * DPI * (double)t / (double)NPO;
        tbl[t] = make_float2((float)cos(a), (float)sin(a));
    }
    __syncthreads();
    int idx = blockIdx.x * 256 + tid;
    if (idx >= CC * NPO * NCO) return;
    int c = idx % NCO, r = (idx / NCO) % NPO, ch = idx / (NCO * NPO);
    int ky = r - 128;
    const float2* t = To + (ch * PSO) * NCO + c;
    float2 acc = make_float2(0.f, 0.f);
    for (int y = 0; y < PSO; y++) {
        float2 w = tbl[(ky * y) & (NPO - 1)];
        float2 v = t[y * NCO];
        acc.x = fmaf(v.x, w.x, acc.x); acc.x = fmaf(-v.y, w.y, acc.x);
        acc.y = fmaf(v.x, w.y, acc.y); acc.y = fmaf(v.y, w.x, acc.y);
    }
    Fo[idx] = acc;
}

// ---------------- resample + combine: kfinal = m_i / pm_i * po_i ----------------
__global__ __launch_bounds__(256) void sampler(const float2* __restrict__ Fm,
                                               const float2* __restrict__ Fp,
                                               const float2* __restrict__ Fo,
                                               float2* __restrict__ KF) {
    __shared__ float2 t8[8];
    __shared__ float2 t192[NPM];
    __shared__ float2 t256[NPO];
    int tid = threadIdx.x;
    if (tid < 8) {
        double a = 2.0 * DPI * (double)tid / 8.0;
        t8[tid] = make_float2((float)cos(a), (float)sin(a));
    }
    for (int t = tid; t < NPM; t += 256) {
        double a = 2.0 * DPI * (double)t / (double)NPM;
        t192[t] = make_float2((float)cos(a), (float)sin(a));
    }
    {
        double a = 2.0 * DPI * (double)tid / (double)NPO;
        t256[tid] = make_float2((float)cos(a), (float)sin(a));
    }
    __syncthreads();
    int idx = blockIdx.x * 256 + tid;
    if (idx >= CC * TT * KXN) return;
    int j = idx % KXN, i = (idx / KXN) % TT, ch = idx / (KXN * TT);

    float fkx = (float)j;
    float fky = (float)(i - 129);

    const float CS  = (float)0.9987502603949669;   // cos(0.05)
    const float SN  = (float)0.04997916927067832;  // sin(0.05)
    const float SCM = (float)(2048.0 * 0.2 / (257.0 * 0.4));
    const float SCP = (float)(192.0  * 0.2 / (257.0 * 0.4));
    const float SCO = (float)(256.0  * 0.4 / (257.0 * 0.4));

    // ---- model image ----
    float2 vm;
    {
        float fx = fkx * SCM, fy = fky * SCM;
        float fxr = CS * fx - SN * fy;
        float fyr = SN * fx + CS * fy;
        bool neg = fxr < 0.0f;
        float fxs = neg ? -fxr : fxr;
        float fys = neg ? -fyr : fyr;
        float rows = fys + 1024.0f, cols = fxs;
        float r0f = floorf(rows), c0f = floorf(cols);
        int r0 = (int)r0f, c0 = (int)c0f;
        float dr = rows - r0f, dc = cols - c0f;
        float2 g[2][2];
        #pragma unroll
        for (int a = 0; a < 2; a++)
            #pragma unroll
            for (int b = 0; b < 2; b++) {
                int r = r0 + a, c = c0 + b;
                float2 v = make_float2(0.f, 0.f);
                if (r >= R_LO && r < R_LO + NRM && c >= 0 && c < NCM) {
                    float2 f = Fm[((size_t)ch * NRM + (r - R_LO)) * NCM + c];
                    v = cmulf2(t8[(r - 1024 + c) & 7], f);
                }
                g[a][b] = v;
            }
        float w00 = (1.f - dr) * (1.f - dc), w10 = dr * (1.f - dc);
        float w01 = (1.f - dr) * dc,         w11 = dr * dc;
        vm.x = g[0][0].x * w00 + g[1][0].x * w10 + g[0][1].x * w01 + g[1][1].x * w11;
        vm.y = g[0][0].y * w00 + g[1][0].y * w10 + g[0][1].y * w01 + g[1][1].y * w11;
        if (neg) vm.y = -vm.y;
    }

    // ---- model psf ----
    float2 vp;
    {
        float fx = fkx * SCP, fy = fky * SCP;
        float fxr = CS * fx - SN * fy;
        float fyr = SN * fx + CS * fy;
        bool neg = fxr < 0.0f;
        float fxs = neg ? -fxr : fxr;
        float fys = neg ? -fyr : fyr;
        float rows = fys + 96.0f, cols = fxs;
        float r0f = floorf(rows), c0f = floorf(cols);
        int r0 = (int)r0f, c0 = (int)c0f;
        float dr = rows - r0f, dc = cols - c0f;
        float2 g[2][2];
        #pragma unroll
        for (int a = 0; a < 2; a++)
            #pragma unroll
            for (int b = 0; b < 2; b++) {
                int r = r0 + a, c = c0 + b;
                float2 v = make_float2(0.f, 0.f);
                if (r >= PR_LO && r < PR_LO + PNR && c >= 0 && c < PNC) {
                    float2 f = Fp[((size_t)ch * PNR + (r - PR_LO)) * PNC + c];
                    int k = r - 96 + c;
                    int tph = (21 * k) % NPM; if (tph < 0) tph += NPM;
                    v = cmulf2(t192[tph], f);
                }
                g[a][b] = v;
            }
        float w00 = (1.f - dr) * (1.f - dc), w10 = dr * (1.f - dc);
        float w01 = (1.f - dr) * dc,         w11 = dr * dc;
        vp.x = g[0][0].x * w00 + g[1][0].x * w10 + g[0][1].x * w01 + g[1][1].x * w11;
        vp.y = g[0][0].y * w00 + g[1][0].y * w10 + g[0][1].y * w01 + g[1][1].y * w11;
        if (neg) vp.y = -vp.y;
    }

    // ---- obs psf (no rotation/flip; fx >= 0 so never conjugated) ----
    float2 vo;
    {
        float fx = fkx * SCO, fy = fky * SCO;
        float rows = fy + 128.0f, cols = fx;
        float r0f = floorf(rows), c0f = floorf(cols);
        int r0 = (int)r0f, c0 = (int)c0f;
        float dr = rows - r0f, dc = cols - c0f;
        float2 g[2][2];
        #pragma unroll
        for (int a = 0; a < 2; a++)
            #pragma unroll
            for (int b = 0; b < 2; b++) {
                int r = r0 + a, c = c0 + b;
                float2 v = make_float2(0.f, 0.f);
                if (r >= 0 && r < NPO && c >= 0 && c < NCO) {
                    float2 f = Fo[((size_t)ch * NPO + r) * NCO + c];
                    int tph = (31 * (r - 128 + c)) & (NPO - 1);
                    v = cmulf2(t256[tph], f);
                }
                g[a][b] = v;
            }
        float w00 = (1.f - dr) * (1.f - dc), w10 = dr * (1.f - dc);
        float w01 = (1.f - dr) * dc,         w11 = dr * dc;
        vo.x = g[0][0].x * w00 + g[1][0].x * w10 + g[0][1].x * w01 + g[1][1].x * w11;
        vo.y = g[0][0].y * w00 + g[1][0].y * w10 + g[0][1].y * w01 + g[1][1].y * w11;
    }

    // kfinal = vm / vp * vo
    float den = vp.x * vp.x + vp.y * vp.y;
    float2 q = make_float2((vm.x * vp.x + vm.y * vp.y) / den,
                           (vm.y * vp.x - vm.x * vp.y) / den);
    KF[idx] = cmulf2(q, vo);
}

// ---------------- inverse, stage 1: row DFT at the 220 needed output rows ----------------
// A[ch][mr][kx] = sum_r kwrap[r][kx] * exp(2*pi*i*r*(m+128)/256), m = 18+mr
// kwrap[r] = kfinal[r] + (r==0)*kfinal[256]   (row 256 aliases row 0: -129 == 127 mod 256)
__global__ __launch_bounds__(128) void inv1(const float2* __restrict__ KF,
                                            float2* __restrict__ Ai) {
    __shared__ float2 t256[NPO];
    int tid = threadIdx.x;
    for (int t = tid; t < NPO; t += 128) {
        double a = 2.0 * DPI * (double)t / (double)NPO;
        t256[t] = make_float2((float)cos(a), (float)sin(a));
    }
    __syncthreads();
    int mr = blockIdx.x, ch = blockIdx.y;
    int mp = 18 + mr + 128;  // m + 128 folds the ifftshift row-offset into the twiddle
    int kx = tid;
    const float2* base = KF + (size_t)ch * TT * KXN;
    float2 fold = base[256 * KXN + kx];
    float2 acc = make_float2(0.f, 0.f);
    for (int r = 0; r < 256; r++) {
        float2 kv = base[r * KXN + kx];
        if (r == 0) { kv.x += fold.x; kv.y += fold.y; }
        float2 tw = t256[(r * mp) & (NPO - 1)];
        acc.x = fmaf(kv.x, tw.x, acc.x); acc.x = fmaf(-kv.y, tw.y, acc.x);
        acc.y = fmaf(kv.x, tw.y, acc.y); acc.y = fmaf(kv.y, tw.x, acc.y);
    }
    Ai[((size_t)ch * OBS + mr) * 128 + kx] = acc;
}

// ---------------- inverse, stage 2: real output at 220 needed cols ----------------
// out = (1/65536) * (-1)^mr * [ Re A0 + 2 * sum_{k=1..127} Re(A_k * exp(2*pi*i*k*(n+128)/256)) ]
__global__ __launch_bounds__(256) void inv2(const float2* __restrict__ Ai,
                                            float* __restrict__ out) {
    __shared__ float2 t256[NPO];
    __shared__ float2 arow[128];
    int tid = threadIdx.x;
    {
        double a = 2.0 * DPI * (double)tid / (double)NPO;
        t256[tid] = make_float2((float)cos(a), (float)sin(a));
    }
    int mr = blockIdx.x, ch = blockIdx.y;
    if (tid < 128) arow[tid] = Ai[((size_t)ch * OBS + mr) * 128 + tid];
    __syncthreads();
    if (tid >= OBS) return;
    int np = 18 + tid + 128;  // n + 128 folds the ifftshift col-offset
    float s = arow[0].x;
    for (int k = 1; k < 128; k++) {
        float2 a = arow[k];
        float2 tw = t256[(k * np) & (NPO - 1)];
        s += 2.0f * (a.x * tw.x - a.y * tw.y);
    }
    s *= (1.0f / 65536.0f);
    if (mr & 1) s = -s;
    out[((size_t)ch * OBS + mr) * OBS + tid] = s;
}

// ---------------- launch ----------------
extern "C" void kernel_launch(void* const* d_in, const int* in_sizes, int n_in,
                              void* d_out, int out_size, void* d_ws, size_t ws_size,
                              hipStream_t stream) {
    const float* model = (const float*)d_in[0];
    const float* psfm  = (const float*)d_in[1];
    const float* psfo  = (const float*)d_in[2];
    float* out = (float*)d_out;

    float2* ws = (float2*)d_ws;
    size_t off = 0;
    float2* W1 = ws + off; off += (size_t)NCM * MHW;       // 294912
    float2* W2 = ws + off; off += (size_t)NRM * MHW;       // 557056
    float2* T1 = ws + off; off += (size_t)CC * MHW * NCM;  // 1474560
    float2* Fm = ws + off; off += (size_t)CC * NRM * NCM;  // 3133440
    float2* Tp = ws + off; off += (size_t)CC * PSM * PNC;
    float2* Fp = ws + off; off += (size_t)CC * PNR * PNC;
    float2* To = ws + off; off += (size_t)CC * PSO * NCO;
    float2* Fo = ws + off; off += (size_t)CC * NPO * NCO;
    float2* KF = ws + off; off += (size_t)CC * TT * KXN;
    float2* Ai = ws + off; off += (size_t)CC * OBS * 128;
    // total ~6.01M float2 = 48.1 MB

    fill_w1<<<(NCM * MHW + 255) / 256, 256, 0, stream>>>(W1);
    fill_w2<<<(NRM * MHW + 255) / 256, 256, 0, stream>>>(W2);

    gemm_m1<<<dim3((CC * MHW) / 64, NCM / 64), 256, 0, stream>>>(model, W1, T1);
    gemm_m2<<<dim3(NRM / 64, NCM / 64, CC), 256, 0, stream>>>(W2, T1, Fm);

    psf_m1<<<(CC * PSM * PNC + 255) / 256, 256, 0, stream>>>(psfm, Tp);
    psf_m2<<<(CC * PNR * PNC + 255) / 256, 256, 0, stream>>>(Tp, Fp);
    psf_o1<<<(CC * PSO * NCO + 255) / 256, 256, 0, stream>>>(psfo, To);
    psf_o2<<<(CC * NPO * NCO + 255) / 256, 256, 0, stream>>>(To, Fo);

    sampler<<<(CC * TT * KXN + 255) / 256, 256, 0, stream>>>(Fm, Fp, Fo, KF);

    inv1<<<dim3(OBS, CC), 128, 0, stream>>>(KF, Ai);
    inv2<<<dim3(OBS, CC), 256, 0, stream>>>(Ai, out);
}

// Round 4
// 249.386 us; speedup vs baseline: 1.4991x; 1.4991x over previous
//
#include <hip/hip_runtime.h>

// ---------------- problem constants ----------------
#define CC   5
#define MHW  512
#define NIM  2048
// model spectrum slab: rows [R_LO, R_LO+NRM), cols [0, NCM)
// sampled region is rows [510,1556), cols [0,537) -- slab padded to 64-multiples
#define R_LO 488
#define NRM  1088
#define NCM  576

#define PSM  41
#define NPM  192
#define PR_LO 40
#define PNR  112
#define PNC  56

#define PSO  61
#define NPO  256
#define NCO  129

#define TT   257
#define KXN  129
#define OBS  220

#define DPI 3.14159265358979323846264338327950288
#define PIF 3.14159265358979f

static __device__ __forceinline__ float2 cmulf2(float2 a, float2 b) {
    return make_float2(a.x * b.x - a.y * b.y, a.x * b.y + a.y * b.x);
}

// ---------------- twiddle table for gemm_m1 ----------------
// W1[c*512+x] = exp(-2*pi*i*c*x/2048), c in [0,NCM)
__global__ void fill_w1(float2* __restrict__ W1) {
    int idx = blockIdx.x * 256 + threadIdx.x;
    if (idx >= NCM * MHW) return;
    int c = idx >> 9, x = idx & 511;
    int t = (c * x) & (NIM - 1);
    double a = -2.0 * DPI * (double)t / (double)NIM;
    W1[idx] = make_float2((float)cos(a), (float)sin(a));
}

// ---------------- stage 1: T1t[(ch*576+n)*512+y] = sum_x model[ch,y,x] * W1[n][x] ----
// m = ch*512+y in [0,2560), n in [0,576), K=512.  real x complex.
// lane map: tx -> m (so the transposed store is contiguous in y), ty -> n.
__global__ __launch_bounds__(256) void gemm_m1(const float* __restrict__ A,
                                               const float2* __restrict__ W,
                                               float2* __restrict__ T1t) {
    __shared__ float  As[16][64 + 1];
    __shared__ float2 Ws[16][64];
    int bm = blockIdx.x * 64, bn = blockIdx.y * 64;
    int tid = threadIdx.x;
    int tx = tid & 15, ty = tid >> 4;
    float2 acc[4][4];
    #pragma unroll
    for (int i = 0; i < 4; i++)
        #pragma unroll
        for (int j = 0; j < 4; j++) acc[i][j] = make_float2(0.f, 0.f);
    for (int k0 = 0; k0 < 512; k0 += 16) {
        #pragma unroll
        for (int l = 0; l < 4; l++) {
            int idx = tid + l * 256;
            int ml = idx >> 4, kl = idx & 15;
            As[kl][ml] = A[(bm + ml) * 512 + k0 + kl];
        }
        #pragma unroll
        for (int l = 0; l < 4; l++) {
            int idx = tid + l * 256;
            int nl = idx >> 4, kl = idx & 15;
            Ws[kl][nl] = W[(bn + nl) * 512 + k0 + kl];
        }
        __syncthreads();
        #pragma unroll
        for (int k = 0; k < 16; k++) {
            float a[4]; float2 w[4];
            #pragma unroll
            for (int i = 0; i < 4; i++) a[i] = As[k][tx + 16 * i];
            #pragma unroll
            for (int j = 0; j < 4; j++) w[j] = Ws[k][ty + 16 * j];
            #pragma unroll
            for (int i = 0; i < 4; i++)
                #pragma unroll
                for (int j = 0; j < 4; j++) {
                    acc[i][j].x = fmaf(a[i], w[j].x, acc[i][j].x);
                    acc[i][j].y = fmaf(a[i], w[j].y, acc[i][j].y);
                }
        }
        __syncthreads();
    }
    #pragma unroll
    for (int i = 0; i < 4; i++)
        #pragma unroll
        for (int j = 0; j < 4; j++) {
            int m = bm + tx + 16 * i, n = bn + ty + 16 * j;
            int ch = m >> 9, y = m & 511;
            T1t[((size_t)(ch * NCM + n)) * 512 + y] = acc[i][j];
        }
}

// ---------------- stage 2: column FFT (replaces the 12.8-GFLOP complex GEMM) ----
// For col = ch*576+n: F(k) = sum_{y<512} T1t[col][y] e^{-2pi i k y/2048},
// needed at k = m-536, m in [0,1088).  k = 4u+v:
//   F(4u+v) = DFT_512( T1t[col][y] * e^{-2pi i v y/2048} )[u]
// Stockham radix-2 in LDS, window-extract, transposed coalesced store.
__global__ __launch_bounds__(256) void fft_col(const float2* __restrict__ T1t,
                                               float2* __restrict__ Fmt) {
    __shared__ float2 Ab[512];
    __shared__ float2 Bb[512];
    __shared__ float2 tw[256];    // tw[t] = exp(-2pi i t/512)
    __shared__ float2 outw[1088];
    int tid = threadIdx.x;
    int col = blockIdx.x;         // ch*576 + n
    {
        float th = (float)tid * (-2.0f * PIF / 512.0f);
        float s, c; __sincosf(th, &s, &c);
        tw[tid] = make_float2(c, s);
    }
    float2 x0 = T1t[(size_t)col * 512 + tid];
    float2 x1 = T1t[(size_t)col * 512 + 256 + tid];
    __syncthreads();
    for (int v = 0; v < 4; v++) {
        // chirp modulate into Ab
        {
            float th0 = (float)(v * tid) * (-2.0f * PIF / 2048.0f);
            float th1 = (float)(v * (tid + 256)) * (-2.0f * PIF / 2048.0f);
            float s0, c0, s1, c1;
            __sincosf(th0, &s0, &c0);
            __sincosf(th1, &s1, &c1);
            Ab[tid]       = cmulf2(make_float2(c0, s0), x0);
            Ab[tid + 256] = cmulf2(make_float2(c1, s1), x1);
        }
        __syncthreads();
        float2 *src = Ab, *dst = Bb;
        #pragma unroll
        for (int s = 0; s < 9; s++) {
            int Ns = 1 << s;
            int jm = tid & (Ns - 1);
            float2 v0 = src[tid];
            float2 v1 = cmulf2(tw[jm << (8 - s)], src[tid + 256]);
            int idxD = ((tid >> s) << (s + 1)) + jm;
            dst[idxD]      = make_float2(v0.x + v1.x, v0.y + v1.y);
            dst[idxD + Ns] = make_float2(v0.x - v1.x, v0.y - v1.y);
            float2* t = src; src = dst; dst = t;
            __syncthreads();
        }
        // src holds D[u] = F(4u+v); extract window k in [-536,552) -> m = k+536
        #pragma unroll
        for (int h = 0; h < 2; h++) {
            int u = tid + h * 256;
            int kr = 4 * u + v;
            if (kr <= 551)       outw[kr + 536]  = src[u];
            else if (kr >= 1512) outw[kr - 1512] = src[u];
        }
        __syncthreads();
    }
    for (int m = tid; m < 1088; m += 256)
        Fmt[(size_t)col * 1088 + m] = outw[m];
}

// ---------------- psf_model partial DFT (tiny) ----------------
__global__ void psf_m1(const float* __restrict__ psf, float2* __restrict__ Tp) {
    __shared__ float2 tbl[NPM];
    int tid = threadIdx.x;
    for (int t = tid; t < NPM; t += 256) {
        double a = -2.0 * DPI * (double)t / (double)NPM;
        tbl[t] = make_float2((float)cos(a), (float)sin(a));
    }
    __syncthreads();
    int idx = blockIdx.x * 256 + tid;
    if (idx >= CC * PSM * PNC) return;
    int c = idx % PNC, y = (idx / PNC) % PSM, ch = idx / (PNC * PSM);
    const float* p = psf + (ch * PSM + y) * PSM;
    float2 acc = make_float2(0.f, 0.f);
    for (int x = 0; x < PSM; x++) {
        float2 w = tbl[(c * x) % NPM];
        float v = p[x];
        acc.x = fmaf(v, w.x, acc.x);
        acc.y = fmaf(v, w.y, acc.y);
    }
    Tp[idx] = acc;
}

__global__ void psf_m2(const float2* __restrict__ Tp, float2* __restrict__ Fp) {
    __shared__ float2 tbl[NPM];
    int tid = threadIdx.x;
    for (int t = tid; t < NPM; t += 256) {
        double a = -2.0 * DPI * (double)t / (double)NPM;
        tbl[t] = make_float2((float)cos(a), (float)sin(a));
    }
    __syncthreads();
    int idx = blockIdx.x * 256 + tid;
    if (idx >= CC * PNR * PNC) return;
    int c = idx % PNC, rr = (idx / PNC) % PNR, ch = idx / (PNC * PNR);
    int ky = rr + (PR_LO - 96);
    const float2* t = Tp + (ch * PSM) * PNC + c;
    float2 acc = make_float2(0.f, 0.f);
    for (int y = 0; y < PSM; y++) {
        int tt = (ky * y) % NPM; if (tt < 0) tt += NPM;
        float2 w = tbl[tt];
        float2 v = t[y * PNC];
        acc.x = fmaf(v.x, w.x, acc.x); acc.x = fmaf(-v.y, w.y, acc.x);
        acc.y = fmaf(v.x, w.y, acc.y); acc.y = fmaf(v.y, w.x, acc.y);
    }
    Fp[idx] = acc;
}

// ---------------- psf_obs partial DFT (tiny, full 256x129 grid) ----------------
__global__ void psf_o1(const float* __restrict__ psf, float2* __restrict__ To) {
    __shared__ float2 tbl[NPO];
    int tid = threadIdx.x;
    for (int t = tid; t < NPO; t += 256) {
        double a = -2.0 * DPI * (double)t / (double)NPO;
        tbl[t] = make_float2((float)cos(a), (float)sin(a));
    }
    __syncthreads();
    int idx = blockIdx.x * 256 + tid;
    if (idx >= CC * PSO * NCO) return;
    int c = idx % NCO, y = (idx / NCO) % PSO, ch = idx / (NCO * PSO);
    const float* p = psf + (ch * PSO + y) * PSO;
    float2 acc = make_float2(0.f, 0.f);
    for (int x = 0; x < PSO; x++) {
        float2 w = tbl[(c * x) & (NPO - 1)];
        float v = p[x];
        acc.x = fmaf(v, w.x, acc.x);
        acc.y = fmaf(v, w.y, acc.y);
    }
    To[idx] = acc;
}

__global__ void psf_o2(const float2* __restrict__ To, float2* __restrict__ Fo) {
    __shared__ float2 tbl[NPO];
    int tid = threadIdx.x;
    for (int t = tid; t < NPO; t += 256) {
        double a = -2.0 * DPI * (double)t / (double)NPO;
        tbl[t] = make_float2((float)cos(a), (float)sin(a));
    }
    __syncthreads();
    int idx = blockIdx.x * 256 + tid;
    if (idx >= CC * NPO * NCO) return;
    int c = idx % NCO, r = (idx / NCO) % NPO, ch = idx / (NCO * NPO);
    int ky = r - 128;
    const float2* t = To + (ch * PSO) * NCO + c;
    float2 acc = make_float2(0.f, 0.f);
    for (int y = 0; y < PSO; y++) {
        float2 w = tbl[(ky * y) & (NPO - 1)];
        float2 v = t[y * NCO];
        acc.x = fmaf(v.x, w.x, acc.x); acc.x = fmaf(-v.y, w.y, acc.x);
        acc.y = fmaf(v.x, w.y, acc.y); acc.y = fmaf(v.y, w.x, acc.y);
    }
    Fo[idx] = acc;
}

// ---------------- resample + combine: kfinal = m_i / pm_i * po_i ----------------
__global__ __launch_bounds__(256) void sampler(const float2* __restrict__ Fmt,
                                               const float2* __restrict__ Fp,
                                               const float2* __restrict__ Fo,
                                               float2* __restrict__ KF) {
    __shared__ float2 t8[8];
    __shared__ float2 t192[NPM];
    __shared__ float2 t256[NPO];
    int tid = threadIdx.x;
    if (tid < 8) {
        double a = 2.0 * DPI * (double)tid / 8.0;
        t8[tid] = make_float2((float)cos(a), (float)sin(a));
    }
    for (int t = tid; t < NPM; t += 256) {
        double a = 2.0 * DPI * (double)t / (double)NPM;
        t192[t] = make_float2((float)cos(a), (float)sin(a));
    }
    {
        double a = 2.0 * DPI * (double)tid / (double)NPO;
        t256[tid] = make_float2((float)cos(a), (float)sin(a));
    }
    __syncthreads();
    int idx = blockIdx.x * 256 + tid;
    if (idx >= CC * TT * KXN) return;
    int j = idx % KXN, i = (idx / KXN) % TT, ch = idx / (KXN * TT);

    float fkx = (float)j;
    float fky = (float)(i - 129);

    const float CS  = (float)0.9987502603949669;   // cos(0.05)
    const float SN  = (float)0.04997916927067832;  // sin(0.05)
    const float SCM = (float)(2048.0 * 0.2 / (257.0 * 0.4));
    const float SCP = (float)(192.0  * 0.2 / (257.0 * 0.4));
    const float SCO = (float)(256.0  * 0.4 / (257.0 * 0.4));

    // ---- model image (Fmt is [ch][n][m] transposed) ----
    float2 vm;
    {
        float fx = fkx * SCM, fy = fky * SCM;
        float fxr = CS * fx - SN * fy;
        float fyr = SN * fx + CS * fy;
        bool neg = fxr < 0.0f;
        float fxs = neg ? -fxr : fxr;
        float fys = neg ? -fyr : fyr;
        float rows = fys + 1024.0f, cols = fxs;
        float r0f = floorf(rows), c0f = floorf(cols);
        int r0 = (int)r0f, c0 = (int)c0f;
        float dr = rows - r0f, dc = cols - c0f;
        float2 g[2][2];
        #pragma unroll
        for (int a = 0; a < 2; a++)
            #pragma unroll
            for (int b = 0; b < 2; b++) {
                int r = r0 + a, c = c0 + b;
                float2 v = make_float2(0.f, 0.f);
                if (r >= R_LO && r < R_LO + NRM && c >= 0 && c < NCM) {
                    float2 f = Fmt[((size_t)ch * NCM + c) * NRM + (r - R_LO)];
                    v = cmulf2(t8[(r - 1024 + c) & 7], f);
                }
                g[a][b] = v;
            }
        float w00 = (1.f - dr) * (1.f - dc), w10 = dr * (1.f - dc);
        float w01 = (1.f - dr) * dc,         w11 = dr * dc;
        vm.x = g[0][0].x * w00 + g[1][0].x * w10 + g[0][1].x * w01 + g[1][1].x * w11;
        vm.y = g[0][0].y * w00 + g[1][0].y * w10 + g[0][1].y * w01 + g[1][1].y * w11;
        if (neg) vm.y = -vm.y;
    }

    // ---- model psf ----
    float2 vp;
    {
        float fx = fkx * SCP, fy = fky * SCP;
        float fxr = CS * fx - SN * fy;
        float fyr = SN * fx + CS * fy;
        bool neg = fxr < 0.0f;
        float fxs = neg ? -fxr : fxr;
        float fys = neg ? -fyr : fyr;
        float rows = fys + 96.0f, cols = fxs;
        float r0f = floorf(rows), c0f = floorf(cols);
        int r0 = (int)r0f, c0 = (int)c0f;
        float dr = rows - r0f, dc = cols - c0f;
        float2 g[2][2];
        #pragma unroll
        for (int a = 0; a < 2; a++)
            #pragma unroll
            for (int b = 0; b < 2; b++) {
                int r = r0 + a, c = c0 + b;
                float2 v = make_float2(0.f, 0.f);
                if (r >= PR_LO && r < PR_LO + PNR && c >= 0 && c < PNC) {
                    float2 f = Fp[((size_t)ch * PNR + (r - PR_LO)) * PNC + c];
                    int k = r - 96 + c;
                    int tph = (21 * k) % NPM; if (tph < 0) tph += NPM;
                    v = cmulf2(t192[tph], f);
                }
                g[a][b] = v;
            }
        float w00 = (1.f - dr) * (1.f - dc), w10 = dr * (1.f - dc);
        float w01 = (1.f - dr) * dc,         w11 = dr * dc;
        vp.x = g[0][0].x * w00 + g[1][0].x * w10 + g[0][1].x * w01 + g[1][1].x * w11;
        vp.y = g[0][0].y * w00 + g[1][0].y * w10 + g[0][1].y * w01 + g[1][1].y * w11;
        if (neg) vp.y = -vp.y;
    }

    // ---- obs psf (no rotation/flip; fx >= 0 so never conjugated) ----
    float2 vo;
    {
        float fx = fkx * SCO, fy = fky * SCO;
        float rows = fy + 128.0f, cols = fx;
        float r0f = floorf(rows), c0f = floorf(cols);
        int r0 = (int)r0f, c0 = (int)c0f;
        float dr = rows - r0f, dc = cols - c0f;
        float2 g[2][2];
        #pragma unroll
        for (int a = 0; a < 2; a++)
            #pragma unroll
            for (int b = 0; b < 2; b++) {
                int r = r0 + a, c = c0 + b;
                float2 v = make_float2(0.f, 0.f);
                if (r >= 0 && r < NPO && c >= 0 && c < NCO) {
                    float2 f = Fo[((size_t)ch * NPO + r) * NCO + c];
                    int tph = (31 * (r - 128 + c)) & (NPO - 1);
                    v = cmulf2(t256[tph], f);
                }
                g[a][b] = v;
            }
        float w00 = (1.f - dr) * (1.f - dc), w10 = dr * (1.f - dc);
        float w01 = (1.f - dr) * dc,         w11 = dr * dc;
        vo.x = g[0][0].x * w00 + g[1][0].x * w10 + g[0][1].x * w01 + g[1][1].x * w11;
        vo.y = g[0][0].y * w00 + g[1][0].y * w10 + g[0][1].y * w01 + g[1][1].y * w11;
    }

    // kfinal = vm / vp * vo
    float den = vp.x * vp.x + vp.y * vp.y;
    float2 q = make_float2((vm.x * vp.x + vm.y * vp.y) / den,
                           (vm.y * vp.x - vm.x * vp.y) / den);
    KF[idx] = cmulf2(q, vo);
}

// ---------------- inverse, stage 1: row DFT at the 220 needed output rows ----------------
// A[ch][mr][kx] = sum_r kwrap[r][kx] * exp(2*pi*i*r*(m+128)/256), m = 18+mr
// kwrap[r] = kfinal[r] + (r==0)*kfinal[256]   (row 256 aliases row 0: -129 == 127 mod 256)
__global__ __launch_bounds__(128) void inv1(const float2* __restrict__ KF,
                                            float2* __restrict__ Ai) {
    __shared__ float2 t256[NPO];
    int tid = threadIdx.x;
    for (int t = tid; t < NPO; t += 128) {
        double a = 2.0 * DPI * (double)t / (double)NPO;
        t256[t] = make_float2((float)cos(a), (float)sin(a));
    }
    __syncthreads();
    int mr = blockIdx.x, ch = blockIdx.y;
    int mp = 18 + mr + 128;  // m + 128 folds the ifftshift row-offset into the twiddle
    int kx = tid;
    const float2* base = KF + (size_t)ch * TT * KXN;
    float2 fold = base[256 * KXN + kx];
    float2 acc = make_float2(0.f, 0.f);
    for (int r = 0; r < 256; r++) {
        float2 kv = base[r * KXN + kx];
        if (r == 0) { kv.x += fold.x; kv.y += fold.y; }
        float2 tw = t256[(r * mp) & (NPO - 1)];
        acc.x = fmaf(kv.x, tw.x, acc.x); acc.x = fmaf(-kv.y, tw.y, acc.x);
        acc.y = fmaf(kv.x, tw.y, acc.y); acc.y = fmaf(kv.y, tw.x, acc.y);
    }
    Ai[((size_t)ch * OBS + mr) * 128 + kx] = acc;
}

// ---------------- inverse, stage 2: real output at 220 needed cols ----------------
// out = (1/65536) * (-1)^mr * [ Re A0 + 2 * sum_{k=1..127} Re(A_k * exp(2*pi*i*k*(n+128)/256)) ]
__global__ __launch_bounds__(256) void inv2(const float2* __restrict__ Ai,
                                            float* __restrict__ out) {
    __shared__ float2 t256[NPO];
    __shared__ float2 arow[128];
    int tid = threadIdx.x;
    {
        double a = 2.0 * DPI * (double)tid / (double)NPO;
        t256[tid] = make_float2((float)cos(a), (float)sin(a));
    }
    int mr = blockIdx.x, ch = blockIdx.y;
    if (tid < 128) arow[tid] = Ai[((size_t)ch * OBS + mr) * 128 + tid];
    __syncthreads();
    if (tid >= OBS) return;
    int np = 18 + tid + 128;  // n + 128 folds the ifftshift col-offset
    float s = arow[0].x;
    for (int k = 1; k < 128; k++) {
        float2 a = arow[k];
        float2 tw = t256[(k * np) & (NPO - 1)];
        s += 2.0f * (a.x * tw.x - a.y * tw.y);
    }
    s *= (1.0f / 65536.0f);
    if (mr & 1) s = -s;
    out[((size_t)ch * OBS + mr) * OBS + tid] = s;
}

// ---------------- launch ----------------
extern "C" void kernel_launch(void* const* d_in, const int* in_sizes, int n_in,
                              void* d_out, int out_size, void* d_ws, size_t ws_size,
                              hipStream_t stream) {
    const float* model = (const float*)d_in[0];
    const float* psfm  = (const float*)d_in[1];
    const float* psfo  = (const float*)d_in[2];
    float* out = (float*)d_out;

    float2* ws = (float2*)d_ws;
    size_t off = 0;
    float2* W1  = ws + off; off += (size_t)NCM * MHW;        // 294912
    float2* T1t = ws + off; off += (size_t)CC * NCM * MHW;   // 1474560  [ch][n][y]
    float2* Fmt = ws + off; off += (size_t)CC * NCM * NRM;   // 3133440  [ch][n][m]
    float2* Tp  = ws + off; off += (size_t)CC * PSM * PNC;
    float2* Fp  = ws + off; off += (size_t)CC * PNR * PNC;
    float2* To  = ws + off; off += (size_t)CC * PSO * NCO;
    float2* Fo  = ws + off; off += (size_t)CC * NPO * NCO;
    float2* KF  = ws + off; off += (size_t)CC * TT * KXN;
    float2* Ai  = ws + off; off += (size_t)CC * OBS * 128;
    // total ~5.5M float2 = 44 MB

    fill_w1<<<(NCM * MHW + 255) / 256, 256, 0, stream>>>(W1);

    gemm_m1<<<dim3((CC * MHW) / 64, NCM / 64), 256, 0, stream>>>(model, W1, T1t);
    fft_col<<<CC * NCM, 256, 0, stream>>>(T1t, Fmt);

    psf_m1<<<(CC * PSM * PNC + 255) / 256, 256, 0, stream>>>(psfm, Tp);
    psf_m2<<<(CC * PNR * PNC + 255) / 256, 256, 0, stream>>>(Tp, Fp);
    psf_o1<<<(CC * PSO * NCO + 255) / 256, 256, 0, stream>>>(psfo, To);
    psf_o2<<<(CC * NPO * NCO + 255) / 256, 256, 0, stream>>>(To, Fo);

    sampler<<<(CC * TT * KXN + 255) / 256, 256, 0, stream>>>(Fmt, Fp, Fo, KF);

    inv1<<<dim3(OBS, CC), 128, 0, stream>>>(KF, Ai);
    inv2<<<dim3(OBS, CC), 256, 0, stream>>>(Ai, out);
}

// Round 7
// 183.323 us; speedup vs baseline: 2.0393x; 1.3604x over previous
//
#include <hip/hip_runtime.h>

// ---------------- problem constants ----------------
#define CC   5
#define MHW  512
#define NIM  2048
#define R_LO 488
#define NRM  1088
#define NCM  576

#define PSM  41
#define NPM  192
#define PR_LO 40
#define PNR  112
#define PNC  56

#define PSO  61
#define NPO  256
#define NCO  129

#define TT   257
#define KXN  129
#define OBS  220

#define DPI 3.14159265358979323846264338327950288
#define PIF 3.14159265358979f

static __device__ __forceinline__ float2 cmulf2(float2 a, float2 b) {
    return make_float2(a.x * b.x - a.y * b.y, a.x * b.y + a.y * b.x);
}

// ================= stage 1: row FFT =================
// T1r[m][c] = sum_x model[m][x] e^{-2pi i c x/2048}, c in [0,576), m = ch*512+y.
// c = 4u+v: F(4u+v) = DFT_512(x[t] * e^{-2pi i v t/2048})[u], keep u < 144.
__global__ __launch_bounds__(256) void fft_row(const float* __restrict__ A,
                                               float2* __restrict__ T1r) {
    __shared__ float2 Ab[512];
    __shared__ float2 Bb[512];
    __shared__ float2 tw[256];     // tw[t] = exp(-2pi i t/512)
    __shared__ float2 outw[NCM];
    int tid = threadIdx.x;
    int row = blockIdx.x;          // ch*512 + y
    {
        float th = (float)tid * (-2.0f * PIF / 512.0f);
        float s, c; __sincosf(th, &s, &c);
        tw[tid] = make_float2(c, s);
    }
    float r0 = A[(size_t)row * 512 + tid];
    float r1 = A[(size_t)row * 512 + 256 + tid];
    __syncthreads();
    for (int v = 0; v < 4; v++) {
        {
            float th0 = (float)(v * tid) * (-2.0f * PIF / 2048.0f);
            float th1 = (float)(v * (tid + 256)) * (-2.0f * PIF / 2048.0f);
            float s0, c0, s1, c1;
            __sincosf(th0, &s0, &c0);
            __sincosf(th1, &s1, &c1);
            Ab[tid]       = make_float2(r0 * c0, r0 * s0);
            Ab[tid + 256] = make_float2(r1 * c1, r1 * s1);
        }
        __syncthreads();
        float2 *src = Ab, *dst = Bb;
        #pragma unroll
        for (int s = 0; s < 9; s++) {
            int Ns = 1 << s;
            int jm = tid & (Ns - 1);
            float2 v0 = src[tid];
            float2 v1 = cmulf2(tw[jm << (8 - s)], src[tid + 256]);
            int idxD = ((tid >> s) << (s + 1)) + jm;
            dst[idxD]      = make_float2(v0.x + v1.x, v0.y + v1.y);
            dst[idxD + Ns] = make_float2(v0.x - v1.x, v0.y - v1.y);
            float2* t = src; src = dst; dst = t;
            __syncthreads();
        }
        if (tid < 144) outw[4 * tid + v] = src[tid];
        __syncthreads();
    }
    for (int c = tid; c < NCM; c += 256)
        T1r[(size_t)row * NCM + c] = outw[c];
}

// ================= stage 2: column FFT =================
// For (ch,n): F(k) = sum_y T1r[(ch*512+y)][n] e^{-2pi i k y/2048}, k = m-536.
// Strided reads (stride 576 float2) served by L2/L3 (adjacent-n blocks share lines).
__global__ __launch_bounds__(256) void fft_col(const float2* __restrict__ T1r,
                                               float2* __restrict__ Fmt) {
    __shared__ float2 Ab[512];
    __shared__ float2 Bb[512];
    __shared__ float2 tw[256];
    __shared__ float2 outw[1088];
    int tid = threadIdx.x;
    int col = blockIdx.x;          // ch*576 + n
    int ch = col / NCM, n = col - ch * NCM;
    {
        float th = (float)tid * (-2.0f * PIF / 512.0f);
        float s, c; __sincosf(th, &s, &c);
        tw[tid] = make_float2(c, s);
    }
    float2 x0 = T1r[((size_t)ch * 512 + tid) * NCM + n];
    float2 x1 = T1r[((size_t)ch * 512 + 256 + tid) * NCM + n];
    __syncthreads();
    for (int v = 0; v < 4; v++) {
        {
            float th0 = (float)(v * tid) * (-2.0f * PIF / 2048.0f);
            float th1 = (float)(v * (tid + 256)) * (-2.0f * PIF / 2048.0f);
            float s0, c0, s1, c1;
            __sincosf(th0, &s0, &c0);
            __sincosf(th1, &s1, &c1);
            Ab[tid]       = cmulf2(make_float2(c0, s0), x0);
            Ab[tid + 256] = cmulf2(make_float2(c1, s1), x1);
        }
        __syncthreads();
        float2 *src = Ab, *dst = Bb;
        #pragma unroll
        for (int s = 0; s < 9; s++) {
            int Ns = 1 << s;
            int jm = tid & (Ns - 1);
            float2 v0 = src[tid];
            float2 v1 = cmulf2(tw[jm << (8 - s)], src[tid + 256]);
            int idxD = ((tid >> s) << (s + 1)) + jm;
            dst[idxD]      = make_float2(v0.x + v1.x, v0.y + v1.y);
            dst[idxD + Ns] = make_float2(v0.x - v1.x, v0.y - v1.y);
            float2* t = src; src = dst; dst = t;
            __syncthreads();
        }
        // window k in [-536,552) -> m = k+536 (F is 2048-periodic)
        #pragma unroll
        for (int h = 0; h < 2; h++) {
            int u = tid + h * 256;
            int kr = 4 * u + v;
            if (kr <= 551)       outw[kr + 536]  = src[u];
            else if (kr >= 1512) outw[kr - 1512] = src[u];
        }
        __syncthreads();
    }
    for (int m = tid; m < 1088; m += 256)
        Fmt[(size_t)col * 1088 + m] = outw[m];
}

// ================= fused psf stage 1 (psf_model x-DFT + psf_obs x-DFT) ======
#define M1B 45    // ceil(5*41*56/256)
#define O1B 154   // ceil(5*61*129/256)
__global__ __launch_bounds__(256) void psf_s1(const float* __restrict__ psfm,
                                              const float* __restrict__ psfo,
                                              float2* __restrict__ Tp,
                                              float2* __restrict__ To) {
    __shared__ float2 t192s[NPM];
    __shared__ float2 t256s[NPO];
    int tid = threadIdx.x;
    for (int t = tid; t < NPM; t += 256) {
        double a = -2.0 * DPI * (double)t / (double)NPM;
        t192s[t] = make_float2((float)cos(a), (float)sin(a));
    }
    {
        double a = -2.0 * DPI * (double)tid / (double)NPO;
        t256s[tid] = make_float2((float)cos(a), (float)sin(a));
    }
    __syncthreads();
    int b = blockIdx.x;
    if (b < M1B) {
        int idx = b * 256 + tid;
        if (idx >= CC * PSM * PNC) return;
        int c = idx % PNC, y = (idx / PNC) % PSM, ch = idx / (PNC * PSM);
        const float* p = psfm + (ch * PSM + y) * PSM;
        float2 acc = make_float2(0.f, 0.f);
        for (int x = 0; x < PSM; x++) {
            float2 w = t192s[(c * x) % NPM];
            float v = p[x];
            acc.x = fmaf(v, w.x, acc.x);
            acc.y = fmaf(v, w.y, acc.y);
        }
        Tp[idx] = acc;
    } else {
        int idx = (b - M1B) * 256 + tid;
        if (idx >= CC * PSO * NCO) return;
        int c = idx % NCO, y = (idx / NCO) % PSO, ch = idx / (NCO * PSO);
        const float* p = psfo + (ch * PSO + y) * PSO;
        float2 acc = make_float2(0.f, 0.f);
        for (int x = 0; x < PSO; x++) {
            float2 w = t256s[(c * x) & (NPO - 1)];
            float v = p[x];
            acc.x = fmaf(v, w.x, acc.x);
            acc.y = fmaf(v, w.y, acc.y);
        }
        To[idx] = acc;
    }
}

// ================= fused psf stage 2 (y-DFTs) =================
#define M2B 123   // ceil(5*112*56/256)
#define O2B 645   // ceil(5*256*129/256)
__global__ __launch_bounds__(256) void psf_s2(const float2* __restrict__ Tp,
                                              const float2* __restrict__ To,
                                              float2* __restrict__ Fp,
                                              float2* __restrict__ Fo) {
    __shared__ float2 t192s[NPM];
    __shared__ float2 t256s[NPO];
    int tid = threadIdx.x;
    for (int t = tid; t < NPM; t += 256) {
        double a = -2.0 * DPI * (double)t / (double)NPM;
        t192s[t] = make_float2((float)cos(a), (float)sin(a));
    }
    {
        double a = -2.0 * DPI * (double)tid / (double)NPO;
        t256s[tid] = make_float2((float)cos(a), (float)sin(a));
    }
    __syncthreads();
    int b = blockIdx.x;
    if (b < M2B) {
        int idx = b * 256 + tid;
        if (idx >= CC * PNR * PNC) return;
        int c = idx % PNC, rr = (idx / PNC) % PNR, ch = idx / (PNC * PNR);
        int ky = rr + (PR_LO - 96);
        const float2* t = Tp + (ch * PSM) * PNC + c;
        float2 acc = make_float2(0.f, 0.f);
        for (int y = 0; y < PSM; y++) {
            int tt = (ky * y) % NPM; if (tt < 0) tt += NPM;
            float2 w = t192s[tt];
            float2 v = t[y * PNC];
            acc.x = fmaf(v.x, w.x, acc.x); acc.x = fmaf(-v.y, w.y, acc.x);
            acc.y = fmaf(v.x, w.y, acc.y); acc.y = fmaf(v.y, w.x, acc.y);
        }
        Fp[idx] = acc;
    } else {
        int idx = (b - M2B) * 256 + tid;
        if (idx >= CC * NPO * NCO) return;
        int c = idx % NCO, r = (idx / NCO) % NPO, ch = idx / (NCO * NPO);
        int ky = r - 128;
        const float2* t = To + (ch * PSO) * NCO + c;
        float2 acc = make_float2(0.f, 0.f);
        for (int y = 0; y < PSO; y++) {
            float2 w = t256s[(ky * y) & (NPO - 1)];
            float2 v = t[y * NCO];
            acc.x = fmaf(v.x, w.x, acc.x); acc.x = fmaf(-v.y, w.y, acc.x);
            acc.y = fmaf(v.x, w.y, acc.y); acc.y = fmaf(v.y, w.x, acc.y);
        }
        Fo[idx] = acc;
    }
}

// ================= resample + combine =================
__global__ __launch_bounds__(256) void sampler(const float2* __restrict__ Fmt,
                                               const float2* __restrict__ Fp,
                                               const float2* __restrict__ Fo,
                                               float2* __restrict__ KF) {
    __shared__ float2 t8[8];
    __shared__ float2 t192[NPM];
    __shared__ float2 t256[NPO];
    int tid = threadIdx.x;
    if (tid < 8) {
        double a = 2.0 * DPI * (double)tid / 8.0;
        t8[tid] = make_float2((float)cos(a), (float)sin(a));
    }
    for (int t = tid; t < NPM; t += 256) {
        double a = 2.0 * DPI * (double)t / (double)NPM;
        t192[t] = make_float2((float)cos(a), (float)sin(a));
    }
    {
        double a = 2.0 * DPI * (double)tid / (double)NPO;
        t256[tid] = make_float2((float)cos(a), (float)sin(a));
    }
    __syncthreads();
    int idx = blockIdx.x * 256 + tid;
    if (idx >= CC * TT * KXN) return;
    int j = idx % KXN, i = (idx / KXN) % TT, ch = idx / (KXN * TT);

    float fkx = (float)j;
    float fky = (float)(i - 129);

    const float CS  = (float)0.9987502603949669;   // cos(0.05)
    const float SN  = (float)0.04997916927067832;  // sin(0.05)
    const float SCM = (float)(2048.0 * 0.2 / (257.0 * 0.4));
    const float SCP = (float)(192.0  * 0.2 / (257.0 * 0.4));
    const float SCO = (float)(256.0  * 0.4 / (257.0 * 0.4));

    // ---- model image (Fmt is [ch][n][m]) ----
    float2 vm;
    {
        float fx = fkx * SCM, fy = fky * SCM;
        float fxr = CS * fx - SN * fy;
        float fyr = SN * fx + CS * fy;
        bool neg = fxr < 0.0f;
        float fxs = neg ? -fxr : fxr;
        float fys = neg ? -fyr : fyr;
        float rows = fys + 1024.0f, cols = fxs;
        float r0f = floorf(rows), c0f = floorf(cols);
        int r0 = (int)r0f, c0 = (int)c0f;
        float dr = rows - r0f, dc = cols - c0f;
        float2 g[2][2];
        #pragma unroll
        for (int a = 0; a < 2; a++)
            #pragma unroll
            for (int b = 0; b < 2; b++) {
                int r = r0 + a, c = c0 + b;
                float2 v = make_float2(0.f, 0.f);
                if (r >= R_LO && r < R_LO + NRM && c >= 0 && c < NCM) {
                    float2 f = Fmt[((size_t)ch * NCM + c) * NRM + (r - R_LO)];
                    v = cmulf2(t8[(r - 1024 + c) & 7], f);
                }
                g[a][b] = v;
            }
        float w00 = (1.f - dr) * (1.f - dc), w10 = dr * (1.f - dc);
        float w01 = (1.f - dr) * dc,         w11 = dr * dc;
        vm.x = g[0][0].x * w00 + g[1][0].x * w10 + g[0][1].x * w01 + g[1][1].x * w11;
        vm.y = g[0][0].y * w00 + g[1][0].y * w10 + g[0][1].y * w01 + g[1][1].y * w11;
        if (neg) vm.y = -vm.y;
    }

    // ---- model psf ----
    float2 vp;
    {
        float fx = fkx * SCP, fy = fky * SCP;
        float fxr = CS * fx - SN * fy;
        float fyr = SN * fx + CS * fy;
        bool neg = fxr < 0.0f;
        float fxs = neg ? -fxr : fxr;
        float fys = neg ? -fyr : fyr;
        float rows = fys + 96.0f, cols = fxs;
        float r0f = floorf(rows), c0f = floorf(cols);
        int r0 = (int)r0f, c0 = (int)c0f;
        float dr = rows - r0f, dc = cols - c0f;
        float2 g[2][2];
        #pragma unroll
        for (int a = 0; a < 2; a++)
            #pragma unroll
            for (int b = 0; b < 2; b++) {
                int r = r0 + a, c = c0 + b;
                float2 v = make_float2(0.f, 0.f);
                if (r >= PR_LO && r < PR_LO + PNR && c >= 0 && c < PNC) {
                    float2 f = Fp[((size_t)ch * PNR + (r - PR_LO)) * PNC + c];
                    int k = r - 96 + c;
                    int tph = (21 * k) % NPM; if (tph < 0) tph += NPM;
                    v = cmulf2(t192[tph], f);
                }
                g[a][b] = v;
            }
        float w00 = (1.f - dr) * (1.f - dc), w10 = dr * (1.f - dc);
        float w01 = (1.f - dr) * dc,         w11 = dr * dc;
        vp.x = g[0][0].x * w00 + g[1][0].x * w10 + g[0][1].x * w01 + g[1][1].x * w11;
        vp.y = g[0][0].y * w00 + g[1][0].y * w10 + g[0][1].y * w01 + g[1][1].y * w11;
        if (neg) vp.y = -vp.y;
    }

    // ---- obs psf ----
    float2 vo;
    {
        float fx = fkx * SCO, fy = fky * SCO;
        float rows = fy + 128.0f, cols = fx;
        float r0f = floorf(rows), c0f = floorf(cols);
        int r0 = (int)r0f, c0 = (int)c0f;
        float dr = rows - r0f, dc = cols - c0f;
        float2 g[2][2];
        #pragma unroll
        for (int a = 0; a < 2; a++)
            #pragma unroll
            for (int b = 0; b < 2; b++) {
                int r = r0 + a, c = c0 + b;
                float2 v = make_float2(0.f, 0.f);
                if (r >= 0 && r < NPO && c >= 0 && c < NCO) {
                    float2 f = Fo[((size_t)ch * NPO + r) * NCO + c];
                    int tph = (31 * (r - 128 + c)) & (NPO - 1);
                    v = cmulf2(t256[tph], f);
                }
                g[a][b] = v;
            }
        float w00 = (1.f - dr) * (1.f - dc), w10 = dr * (1.f - dc);
        float w01 = (1.f - dr) * dc,         w11 = dr * dc;
        vo.x = g[0][0].x * w00 + g[1][0].x * w10 + g[0][1].x * w01 + g[1][1].x * w11;
        vo.y = g[0][0].y * w00 + g[1][0].y * w10 + g[0][1].y * w01 + g[1][1].y * w11;
    }

    float den = vp.x * vp.x + vp.y * vp.y;
    float2 q = make_float2((vm.x * vp.x + vm.y * vp.y) / den,
                           (vm.y * vp.x - vm.x * vp.y) / den);
    KF[idx] = cmulf2(q, vo);
}

// ================= fused inverse (row DFT + col cosine sum) =================
// block (mr, ch): phase 1 computes A[kx] = sum_r kwrap[r][kx] e^{2pi i r(146+mr)/256}
// (r-loop split over 2 thread-halves), phase 2 the 220 real outputs.
__global__ __launch_bounds__(256) void inv12(const float2* __restrict__ KF,
                                             float* __restrict__ out) {
    __shared__ float2 t256[NPO];
    __shared__ float2 part[2][128];
    __shared__ float2 arow[128];
    int tid = threadIdx.x;
    {
        double a = 2.0 * DPI * (double)tid / (double)NPO;
        t256[tid] = make_float2((float)cos(a), (float)sin(a));
    }
    __syncthreads();
    int mr = blockIdx.x, ch = blockIdx.y;
    int mp = 146 + mr;   // (18+mr) + 128 folds ifftshift row offset
    int kx = tid & 127, half = tid >> 7;
    const float2* base = KF + (size_t)ch * TT * KXN;
    float2 acc = make_float2(0.f, 0.f);
    int rlo = half * 128;
    for (int r = rlo; r < rlo + 128; r++) {
        float2 kv = base[r * KXN + kx];
        if (r == 0) {   // fold row 256 (aliases row 0 mod 256)
            float2 fold = base[256 * KXN + kx];
            kv.x += fold.x; kv.y += fold.y;
        }
        float2 tw = t256[(r * mp) & (NPO - 1)];
        acc.x = fmaf(kv.x, tw.x, acc.x); acc.x = fmaf(-kv.y, tw.y, acc.x);
        acc.y = fmaf(kv.x, tw.y, acc.y); acc.y = fmaf(kv.y, tw.x, acc.y);
    }
    part[half][kx] = acc;
    __syncthreads();
    if (tid < 128) {
        float2 a0 = part[0][tid], a1 = part[1][tid];
        arow[tid] = make_float2(a0.x + a1.x, a0.y + a1.y);
    }
    __syncthreads();
    if (tid >= OBS) return;
    int np = 146 + tid;  // (18+tid) + 128 folds ifftshift col offset
    float s = arow[0].x;
    for (int k = 1; k < 128; k++) {
        float2 a = arow[k];
        float2 tw = t256[(k * np) & (NPO - 1)];
        s += 2.0f * (a.x * tw.x - a.y * tw.y);
    }
    s *= (1.0f / 65536.0f);
    if (mr & 1) s = -s;
    out[((size_t)ch * OBS + mr) * OBS + tid] = s;
}

// ---------------- launch ----------------
extern "C" void kernel_launch(void* const* d_in, const int* in_sizes, int n_in,
                              void* d_out, int out_size, void* d_ws, size_t ws_size,
                              hipStream_t stream) {
    const float* model = (const float*)d_in[0];
    const float* psfm  = (const float*)d_in[1];
    const float* psfo  = (const float*)d_in[2];
    float* out = (float*)d_out;

    float2* ws = (float2*)d_ws;
    size_t off = 0;
    float2* T1r = ws + off; off += (size_t)CC * MHW * NCM;   // [m][c] row-major
    float2* Fmt = ws + off; off += (size_t)CC * NCM * NRM;   // [ch][n][m]
    float2* Tp  = ws + off; off += (size_t)CC * PSM * PNC;
    float2* Fp  = ws + off; off += (size_t)CC * PNR * PNC;
    float2* To  = ws + off; off += (size_t)CC * PSO * NCO;
    float2* Fo  = ws + off; off += (size_t)CC * NPO * NCO;
    float2* KF  = ws + off; off += (size_t)CC * TT * KXN;
    // total ~5.1M float2 = 41 MB

    fft_row<<<CC * MHW, 256, 0, stream>>>(model, T1r);
    fft_col<<<CC * NCM, 256, 0, stream>>>(T1r, Fmt);

    psf_s1<<<M1B + O1B, 256, 0, stream>>>(psfm, psfo, Tp, To);
    psf_s2<<<M2B + O2B, 256, 0, stream>>>(Tp, To, Fp, Fo);

    sampler<<<(CC * TT * KXN + 255) / 256, 256, 0, stream>>>(Fmt, Fp, Fo, KF);

    inv12<<<dim3(OBS, CC), 256, 0, stream>>>(KF, out);
}

// Round 11
// 162.187 us; speedup vs baseline: 2.3051x; 1.1303x over previous
//
#include <hip/hip_runtime.h>

// ---------------- problem constants ----------------
#define CC   5
#define MHW  512
#define NIM  2048
#define R_LO 488
#define NRM  1088
#define NCM  576

#define PSM  41
#define NPM  192
#define PR_LO 40
#define PNR  112
#define PNC  56

#define PSO  61
#define NPO  256
#define NCO  129

#define TT   257
#define KXN  129
#define OBS  220

#define DPI 3.14159265358979323846264338327950288
#define PIF 3.14159265358979f

static __device__ __forceinline__ float2 cmulf2(float2 a, float2 b) {
    return make_float2(a.x * b.x - a.y * b.y, a.x * b.y + a.y * b.x);
}

// ================= stage 1: row FFT =================
// T1r[m][c] = sum_x model[m][x] e^{-2pi i c x/2048}, c in [0,576), m = ch*512+y.
// c = 4u+v: F(4u+v) = DFT_512(x[t] * e^{-2pi i v t/2048})[u], keep u < 144.
__global__ __launch_bounds__(256) void fft_row(const float* __restrict__ A,
                                               float2* __restrict__ T1r) {
    __shared__ float2 Ab[512];
    __shared__ float2 Bb[512];
    __shared__ float2 tw[256];     // tw[t] = exp(-2pi i t/512)
    __shared__ float2 outw[NCM];
    int tid = threadIdx.x;
    int row = blockIdx.x;          // ch*512 + y
    {
        float th = (float)tid * (-2.0f * PIF / 512.0f);
        float s, c; __sincosf(th, &s, &c);
        tw[tid] = make_float2(c, s);
    }
    float r0 = A[(size_t)row * 512 + tid];
    float r1 = A[(size_t)row * 512 + 256 + tid];
    __syncthreads();
    for (int v = 0; v < 4; v++) {
        {
            float th0 = (float)(v * tid) * (-2.0f * PIF / 2048.0f);
            float th1 = (float)(v * (tid + 256)) * (-2.0f * PIF / 2048.0f);
            float s0, c0, s1, c1;
            __sincosf(th0, &s0, &c0);
            __sincosf(th1, &s1, &c1);
            Ab[tid]       = make_float2(r0 * c0, r0 * s0);
            Ab[tid + 256] = make_float2(r1 * c1, r1 * s1);
        }
        __syncthreads();
        float2 *src = Ab, *dst = Bb;
        #pragma unroll
        for (int s = 0; s < 9; s++) {
            int Ns = 1 << s;
            int jm = tid & (Ns - 1);
            float2 v0 = src[tid];
            float2 v1 = cmulf2(tw[jm << (8 - s)], src[tid + 256]);
            int idxD = ((tid >> s) << (s + 1)) + jm;
            dst[idxD]      = make_float2(v0.x + v1.x, v0.y + v1.y);
            dst[idxD + Ns] = make_float2(v0.x - v1.x, v0.y - v1.y);
            float2* t = src; src = dst; dst = t;
            __syncthreads();
        }
        if (tid < 144) outw[4 * tid + v] = src[tid];
        __syncthreads();
    }
    for (int c = tid; c < NCM; c += 256)
        T1r[(size_t)row * NCM + c] = outw[c];
}

// ================= stage 2: column FFT =================
// For (ch,n): F(k) = sum_y T1r[(ch*512+y)][n] e^{-2pi i k y/2048}, k = m-536.
__global__ __launch_bounds__(256) void fft_col(const float2* __restrict__ T1r,
                                               float2* __restrict__ Fmt) {
    __shared__ float2 Ab[512];
    __shared__ float2 Bb[512];
    __shared__ float2 tw[256];
    __shared__ float2 outw[1088];
    int tid = threadIdx.x;
    int col = blockIdx.x;          // ch*576 + n
    int ch = col / NCM, n = col - ch * NCM;
    {
        float th = (float)tid * (-2.0f * PIF / 512.0f);
        float s, c; __sincosf(th, &s, &c);
        tw[tid] = make_float2(c, s);
    }
    float2 x0 = T1r[((size_t)ch * 512 + tid) * NCM + n];
    float2 x1 = T1r[((size_t)ch * 512 + 256 + tid) * NCM + n];
    __syncthreads();
    for (int v = 0; v < 4; v++) {
        {
            float th0 = (float)(v * tid) * (-2.0f * PIF / 2048.0f);
            float th1 = (float)(v * (tid + 256)) * (-2.0f * PIF / 2048.0f);
            float s0, c0, s1, c1;
            __sincosf(th0, &s0, &c0);
            __sincosf(th1, &s1, &c1);
            Ab[tid]       = cmulf2(make_float2(c0, s0), x0);
            Ab[tid + 256] = cmulf2(make_float2(c1, s1), x1);
        }
        __syncthreads();
        float2 *src = Ab, *dst = Bb;
        #pragma unroll
        for (int s = 0; s < 9; s++) {
            int Ns = 1 << s;
            int jm = tid & (Ns - 1);
            float2 v0 = src[tid];
            float2 v1 = cmulf2(tw[jm << (8 - s)], src[tid + 256]);
            int idxD = ((tid >> s) << (s + 1)) + jm;
            dst[idxD]      = make_float2(v0.x + v1.x, v0.y + v1.y);
            dst[idxD + Ns] = make_float2(v0.x - v1.x, v0.y - v1.y);
            float2* t = src; src = dst; dst = t;
            __syncthreads();
        }
        // window k in [-536,552) -> m = k+536 (F is 2048-periodic)
        #pragma unroll
        for (int h = 0; h < 2; h++) {
            int u = tid + h * 256;
            int kr = 4 * u + v;
            if (kr <= 551)       outw[kr + 536]  = src[u];
            else if (kr >= 1512) outw[kr - 1512] = src[u];
        }
        __syncthreads();
    }
    for (int m = tid; m < 1088; m += 256)
        Fmt[(size_t)col * 1088 + m] = outw[m];
}

// ================= fused psf stage 1 (psf_model x-DFT + psf_obs x-DFT) ======
#define M1B 45    // ceil(5*41*56/256)
#define O1B 154   // ceil(5*61*129/256)
__global__ __launch_bounds__(256) void psf_s1(const float* __restrict__ psfm,
                                              const float* __restrict__ psfo,
                                              float2* __restrict__ Tp,
                                              float2* __restrict__ To) {
    __shared__ float2 t192s[NPM];
    __shared__ float2 t256s[NPO];
    int tid = threadIdx.x;
    for (int t = tid; t < NPM; t += 256) {
        double a = -2.0 * DPI * (double)t / (double)NPM;
        t192s[t] = make_float2((float)cos(a), (float)sin(a));
    }
    {
        double a = -2.0 * DPI * (double)tid / (double)NPO;
        t256s[tid] = make_float2((float)cos(a), (float)sin(a));
    }
    __syncthreads();
    int b = blockIdx.x;
    if (b < M1B) {
        int idx = b * 256 + tid;
        if (idx >= CC * PSM * PNC) return;
        int c = idx % PNC, y = (idx / PNC) % PSM, ch = idx / (PNC * PSM);
        const float* p = psfm + (ch * PSM + y) * PSM;
        float2 acc = make_float2(0.f, 0.f);
        for (int x = 0; x < PSM; x++) {
            float2 w = t192s[(c * x) % NPM];
            float v = p[x];
            acc.x = fmaf(v, w.x, acc.x);
            acc.y = fmaf(v, w.y, acc.y);
        }
        Tp[idx] = acc;
    } else {
        int idx = (b - M1B) * 256 + tid;
        if (idx >= CC * PSO * NCO) return;
        int c = idx % NCO, y = (idx / NCO) % PSO, ch = idx / (NCO * PSO);
        const float* p = psfo + (ch * PSO + y) * PSO;
        float2 acc = make_float2(0.f, 0.f);
        for (int x = 0; x < PSO; x++) {
            float2 w = t256s[(c * x) & (NPO - 1)];
            float v = p[x];
            acc.x = fmaf(v, w.x, acc.x);
            acc.y = fmaf(v, w.y, acc.y);
        }
        To[idx] = acc;
    }
}

// ================= fused psf stage 2 (y-DFTs) =================
#define M2B 123   // ceil(5*112*56/256)
#define O2B 645   // ceil(5*256*129/256)
__global__ __launch_bounds__(256) void psf_s2(const float2* __restrict__ Tp,
                                              const float2* __restrict__ To,
                                              float2* __restrict__ Fp,
                                              float2* __restrict__ Fo) {
    __shared__ float2 t192s[NPM];
    __shared__ float2 t256s[NPO];
    int tid = threadIdx.x;
    for (int t = tid; t < NPM; t += 256) {
        double a = -2.0 * DPI * (double)t / (double)NPM;
        t192s[t] = make_float2((float)cos(a), (float)sin(a));
    }
    {
        double a = -2.0 * DPI * (double)tid / (double)NPO;
        t256s[tid] = make_float2((float)cos(a), (float)sin(a));
    }
    __syncthreads();
    int b = blockIdx.x;
    if (b < M2B) {
        int idx = b * 256 + tid;
        if (idx >= CC * PNR * PNC) return;
        int c = idx % PNC, rr = (idx / PNC) % PNR, ch = idx / (PNC * PNR);
        int ky = rr + (PR_LO - 96);
        const float2* t = Tp + (ch * PSM) * PNC + c;
        float2 acc = make_float2(0.f, 0.f);
        for (int y = 0; y < PSM; y++) {
            int tt = (ky * y) % NPM; if (tt < 0) tt += NPM;
            float2 w = t192s[tt];
            float2 v = t[y * PNC];
            acc.x = fmaf(v.x, w.x, acc.x); acc.x = fmaf(-v.y, w.y, acc.x);
            acc.y = fmaf(v.x, w.y, acc.y); acc.y = fmaf(v.y, w.x, acc.y);
        }
        Fp[idx] = acc;
    } else {
        int idx = (b - M2B) * 256 + tid;
        if (idx >= CC * NPO * NCO) return;
        int c = idx % NCO, r = (idx / NCO) % NPO, ch = idx / (NCO * NPO);
        int ky = r - 128;
        const float2* t = To + (ch * PSO) * NCO + c;
        float2 acc = make_float2(0.f, 0.f);
        for (int y = 0; y < PSO; y++) {
            float2 w = t256s[(ky * y) & (NPO - 1)];
            float2 v = t[y * NCO];
            acc.x = fmaf(v.x, w.x, acc.x); acc.x = fmaf(-v.y, w.y, acc.x);
            acc.y = fmaf(v.x, w.y, acc.y); acc.y = fmaf(v.y, w.x, acc.y);
        }
        Fo[idx] = acc;
    }
}

// ================= resample + combine =================
__global__ __launch_bounds__(256) void sampler(const float2* __restrict__ Fmt,
                                               const float2* __restrict__ Fp,
                                               const float2* __restrict__ Fo,
                                               float2* __restrict__ KF) {
    __shared__ float2 t8[8];
    __shared__ float2 t192[NPM];
    __shared__ float2 t256[NPO];
    int tid = threadIdx.x;
    if (tid < 8) {
        double a = 2.0 * DPI * (double)tid / 8.0;
        t8[tid] = make_float2((float)cos(a), (float)sin(a));
    }
    for (int t = tid; t < NPM; t += 256) {
        double a = 2.0 * DPI * (double)t / (double)NPM;
        t192[t] = make_float2((float)cos(a), (float)sin(a));
    }
    {
        double a = 2.0 * DPI * (double)tid / (double)NPO;
        t256[tid] = make_float2((float)cos(a), (float)sin(a));
    }
    __syncthreads();
    int idx = blockIdx.x * 256 + tid;
    if (idx >= CC * TT * KXN) return;
    int j = idx % KXN, i = (idx / KXN) % TT, ch = idx / (KXN * TT);

    float fkx = (float)j;
    float fky = (float)(i - 129);

    const float CS  = (float)0.9987502603949669;   // cos(0.05)
    const float SN  = (float)0.04997916927067832;  // sin(0.05)
    const float SCM = (float)(2048.0 * 0.2 / (257.0 * 0.4));
    const float SCP = (float)(192.0  * 0.2 / (257.0 * 0.4));
    const float SCO = (float)(256.0  * 0.4 / (257.0 * 0.4));

    // ---- model image (Fmt is [ch][n][m]) ----
    float2 vm;
    {
        float fx = fkx * SCM, fy = fky * SCM;
        float fxr = CS * fx - SN * fy;
        float fyr = SN * fx + CS * fy;
        bool neg = fxr < 0.0f;
        float fxs = neg ? -fxr : fxr;
        float fys = neg ? -fyr : fyr;
        float rows = fys + 1024.0f, cols = fxs;
        float r0f = floorf(rows), c0f = floorf(cols);
        int r0 = (int)r0f, c0 = (int)c0f;
        float dr = rows - r0f, dc = cols - c0f;
        float2 g[2][2];
        #pragma unroll
        for (int a = 0; a < 2; a++)
            #pragma unroll
            for (int b = 0; b < 2; b++) {
                int r = r0 + a, c = c0 + b;
                float2 v = make_float2(0.f, 0.f);
                if (r >= R_LO && r < R_LO + NRM && c >= 0 && c < NCM) {
                    float2 f = Fmt[((size_t)ch * NCM + c) * NRM + (r - R_LO)];
                    v = cmulf2(t8[(r - 1024 + c) & 7], f);
                }
                g[a][b] = v;
            }
        float w00 = (1.f - dr) * (1.f - dc), w10 = dr * (1.f - dc);
        float w01 = (1.f - dr) * dc,         w11 = dr * dc;
        vm.x = g[0][0].x * w00 + g[1][0].x * w10 + g[0][1].x * w01 + g[1][1].x * w11;
        vm.y = g[0][0].y * w00 + g[1][0].y * w10 + g[0][1].y * w01 + g[1][1].y * w11;
        if (neg) vm.y = -vm.y;
    }

    // ---- model psf ----
    float2 vp;
    {
        float fx = fkx * SCP, fy = fky * SCP;
        float fxr = CS * fx - SN * fy;
        float fyr = SN * fx + CS * fy;
        bool neg = fxr < 0.0f;
        float fxs = neg ? -fxr : fxr;
        float fys = neg ? -fyr : fyr;
        float rows = fys + 96.0f, cols = fxs;
        float r0f = floorf(rows), c0f = floorf(cols);
        int r0 = (int)r0f, c0 = (int)c0f;
        float dr = rows - r0f, dc = cols - c0f;
        float2 g[2][2];
        #pragma unroll
        for (int a = 0; a < 2; a++)
            #pragma unroll
            for (int b = 0; b < 2; b++) {
                int r = r0 + a, c = c0 + b;
                float2 v = make_float2(0.f, 0.f);
                if (r >= PR_LO && r < PR_LO + PNR && c >= 0 && c < PNC) {
                    float2 f = Fp[((size_t)ch * PNR + (r - PR_LO)) * PNC + c];
                    int k = r - 96 + c;
                    int tph = (21 * k) % NPM; if (tph < 0) tph += NPM;
                    v = cmulf2(t192[tph], f);
                }
                g[a][b] = v;
            }
        float w00 = (1.f - dr) * (1.f - dc), w10 = dr * (1.f - dc);
        float w01 = (1.f - dr) * dc,         w11 = dr * dc;
        vp.x = g[0][0].x * w00 + g[1][0].x * w10 + g[0][1].x * w01 + g[1][1].x * w11;
        vp.y = g[0][0].y * w00 + g[1][0].y * w10 + g[0][1].y * w01 + g[1][1].y * w11;
        if (neg) vp.y = -vp.y;
    }

    // ---- obs psf ----
    float2 vo;
    {
        float fx = fkx * SCO, fy = fky * SCO;
        float rows = fy + 128.0f, cols = fx;
        float r0f = floorf(rows), c0f = floorf(cols);
        int r0 = (int)r0f, c0 = (int)c0f;
        float dr = rows - r0f, dc = cols - c0f;
        float2 g[2][2];
        #pragma unroll
        for (int a = 0; a < 2; a++)
            #pragma unroll
            for (int b = 0; b < 2; b++) {
                int r = r0 + a, c = c0 + b;
                float2 v = make_float2(0.f, 0.f);
                if (r >= 0 && r < NPO && c >= 0 && c < NCO) {
                    float2 f = Fo[((size_t)ch * NPO + r) * NCO + c];
                    int tph = (31 * (r - 128 + c)) & (NPO - 1);
                    v = cmulf2(t256[tph], f);
                }
                g[a][b] = v;
            }
        float w00 = (1.f - dr) * (1.f - dc), w10 = dr * (1.f - dc);
        float w01 = (1.f - dr) * dc,         w11 = dr * dc;
        vo.x = g[0][0].x * w00 + g[1][0].x * w10 + g[0][1].x * w01 + g[1][1].x * w11;
        vo.y = g[0][0].y * w00 + g[1][0].y * w10 + g[0][1].y * w01 + g[1][1].y * w11;
    }

    float den = vp.x * vp.x + vp.y * vp.y;
    float2 q = make_float2((vm.x * vp.x + vm.y * vp.y) / den,
                           (vm.y * vp.x - vm.x * vp.y) / den);
    KF[idx] = cmulf2(q, vo);
}

// ================= fused inverse (row DFT + col cosine sum), ILP version ====
// block (mr, ch), 512 threads: phase 1 computes A[kx] = sum_r kwrap[r][kx]
// e^{2pi i r(146+mr)/256} with the 256-term r-sum split over 4 thread-quarters
// and 4-way unrolled (16 loads in flight, broken FMA chains).
// t256 is XOR-swizzled (L = t ^ ((t>>4)&15)) so phase-2's per-lane stride-k
// reads spread across banks instead of 16/32-way conflicting.
#define SWZ(t) ((t) ^ (((t) >> 4) & 15))
__global__ __launch_bounds__(512) void inv12(const float2* __restrict__ KF,
                                             float* __restrict__ out) {
    __shared__ float2 t256[NPO];
    __shared__ float2 part[4][128];
    __shared__ float2 arow[128];
    int tid = threadIdx.x;
    if (tid < NPO) {
        double a = 2.0 * DPI * (double)tid / (double)NPO;
        t256[SWZ(tid)] = make_float2((float)cos(a), (float)sin(a));
    }
    __syncthreads();
    int mr = blockIdx.x, ch = blockIdx.y;
    int mp = 146 + mr;   // (18+mr) + 128 folds ifftshift row offset
    int kx = tid & 127, q = tid >> 7;
    const float2* base = KF + (size_t)ch * TT * KXN + kx;
    float2 a0 = make_float2(0.f, 0.f), a1 = a0, a2 = a0, a3 = a0;
    int rlo = q * 64;
    #pragma unroll 4
    for (int rr = 0; rr < 64; rr += 4) {
        int r = rlo + rr;
        float2 k0 = base[(size_t)(r + 0) * KXN];
        float2 k1 = base[(size_t)(r + 1) * KXN];
        float2 k2 = base[(size_t)(r + 2) * KXN];
        float2 k3 = base[(size_t)(r + 3) * KXN];
        int i0 = ((r + 0) * mp) & 255;
        int i1 = ((r + 1) * mp) & 255;
        int i2 = ((r + 2) * mp) & 255;
        int i3 = ((r + 3) * mp) & 255;
        float2 w0 = t256[SWZ(i0)], w1 = t256[SWZ(i1)];
        float2 w2 = t256[SWZ(i2)], w3 = t256[SWZ(i3)];
        a0.x = fmaf(k0.x, w0.x, a0.x); a0.x = fmaf(-k0.y, w0.y, a0.x);
        a0.y = fmaf(k0.x, w0.y, a0.y); a0.y = fmaf(k0.y, w0.x, a0.y);
        a1.x = fmaf(k1.x, w1.x, a1.x); a1.x = fmaf(-k1.y, w1.y, a1.x);
        a1.y = fmaf(k1.x, w1.y, a1.y); a1.y = fmaf(k1.y, w1.x, a1.y);
        a2.x = fmaf(k2.x, w2.x, a2.x); a2.x = fmaf(-k2.y, w2.y, a2.x);
        a2.y = fmaf(k2.x, w2.y, a2.y); a2.y = fmaf(k2.y, w2.x, a2.y);
        a3.x = fmaf(k3.x, w3.x, a3.x); a3.x = fmaf(-k3.y, w3.y, a3.x);
        a3.y = fmaf(k3.x, w3.y, a3.y); a3.y = fmaf(k3.y, w3.x, a3.y);
    }
    if (q == 0) {   // fold row 256 onto r=0 (twiddle at r=0 is 1)
        float2 fold = base[(size_t)256 * KXN];
        a0.x += fold.x; a0.y += fold.y;
    }
    part[q][kx] = make_float2((a0.x + a1.x) + (a2.x + a3.x),
                              (a0.y + a1.y) + (a2.y + a3.y));
    __syncthreads();
    if (tid < 128) {
        float2 p0 = part[0][tid], p1 = part[1][tid];
        float2 p2 = part[2][tid], p3 = part[3][tid];
        arow[tid] = make_float2((p0.x + p1.x) + (p2.x + p3.x),
                                (p0.y + p1.y) + (p2.y + p3.y));
    }
    __syncthreads();
    if (tid >= OBS) return;
    int np = 146 + tid;  // (18+tid) + 128 folds ifftshift col offset
    float s0 = 0.f, s1 = 0.f, s2 = 0.f, s3 = 0.f;
    #pragma unroll 4
    for (int k = 1; k + 3 <= 127; k += 4) {
        float2 v0 = arow[k + 0], v1 = arow[k + 1];
        float2 v2 = arow[k + 2], v3 = arow[k + 3];
        int i0 = ((k + 0) * np) & 255;
        int i1 = ((k + 1) * np) & 255;
        int i2 = ((k + 2) * np) & 255;
        int i3 = ((k + 3) * np) & 255;
        float2 w0 = t256[SWZ(i0)], w1 = t256[SWZ(i1)];
        float2 w2 = t256[SWZ(i2)], w3 = t256[SWZ(i3)];
        s0 = fmaf(v0.x, w0.x, s0); s0 = fmaf(-v0.y, w0.y, s0);
        s1 = fmaf(v1.x, w1.x, s1); s1 = fmaf(-v1.y, w1.y, s1);
        s2 = fmaf(v2.x, w2.x, s2); s2 = fmaf(-v2.y, w2.y, s2);
        s3 = fmaf(v3.x, w3.x, s3); s3 = fmaf(-v3.y, w3.y, s3);
    }
    for (int k = 125; k < 128; k++) {   // tail
        float2 v = arow[k];
        int i = (k * np) & 255;
        float2 w = t256[SWZ(i)];
        s0 = fmaf(v.x, w.x, s0); s0 = fmaf(-v.y, w.y, s0);
    }
    float s = arow[0].x + 2.0f * ((s0 + s1) + (s2 + s3));
    s *= (1.0f / 65536.0f);
    if (mr & 1) s = -s;
    out[((size_t)ch * OBS + mr) * OBS + tid] = s;
}

// ---------------- launch ----------------
extern "C" void kernel_launch(void* const* d_in, const int* in_sizes, int n_in,
                              void* d_out, int out_size, void* d_ws, size_t ws_size,
                              hipStream_t stream) {
    const float* model = (const float*)d_in[0];
    const float* psfm  = (const float*)d_in[1];
    const float* psfo  = (const float*)d_in[2];
    float* out = (float*)d_out;

    float2* ws = (float2*)d_ws;
    size_t off = 0;
    float2* T1r = ws + off; off += (size_t)CC * MHW * NCM;   // [m][c] row-major
    float2* Fmt = ws + off; off += (size_t)CC * NCM * NRM;   // [ch][n][m]
    float2* Tp  = ws + off; off += (size_t)CC * PSM * PNC;
    float2* Fp  = ws + off; off += (size_t)CC * PNR * PNC;
    float2* To  = ws + off; off += (size_t)CC * PSO * NCO;
    float2* Fo  = ws + off; off += (size_t)CC * NPO * NCO;
    float2* KF  = ws + off; off += (size_t)CC * TT * KXN;
    // total ~5.1M float2 = 41 MB

    fft_row<<<CC * MHW, 256, 0, stream>>>(model, T1r);
    fft_col<<<CC * NCM, 256, 0, stream>>>(T1r, Fmt);

    psf_s1<<<M1B + O1B, 256, 0, stream>>>(psfm, psfo, Tp, To);
    psf_s2<<<M2B + O2B, 256, 0, stream>>>(Tp, To, Fp, Fo);

    sampler<<<(CC * TT * KXN + 255) / 256, 256, 0, stream>>>(Fmt, Fp, Fo, KF);

    inv12<<<dim3(OBS, CC), 512, 0, stream>>>(KF, out);
}